// Round 5
// baseline (695.336 us; speedup 1.0000x reference)
//
#include <hip/hip_runtime.h>
#include <hip/hip_bf16.h>

typedef __hip_bfloat16 bf16;
typedef __attribute__((ext_vector_type(8))) short short8;
typedef __attribute__((ext_vector_type(4))) float floatx4;
typedef __attribute__((ext_vector_type(4))) unsigned short ushortx4;

#define N_NODESC 50000
#define MPAD     50016     // padded to 32-row tiles
#define N_EDGESC 800000
#define E_TOTC   850000    // + self loops
#define IN_DIMC  128
#define FDIM     256       // HEADS*HID
#define HEADSC   4
#define HIDC     64
#define NEG_SLOPE 0.2f
#define CHUNK    32

// k_prep section block counts
#define NB_MEAN  400
#define NB_CVTX  6252      // (MPAD*128/4)/256
#define NB_CVTW  256
#define NB_COUNT 3321      // ceil(E_TOT/256)

__device__ __forceinline__ float bits2f(unsigned short b){
  return __uint_as_float(((unsigned)b) << 16);
}

__device__ __forceinline__ float wave_sum(float v){
  #pragma unroll
  for (int m = 32; m > 0; m >>= 1) v += __shfl_xor(v, m, 64);
  return v;
}
__device__ __forceinline__ float wave_max(float v){
  #pragma unroll
  for (int m = 32; m > 0; m >>= 1) v = fmaxf(v, __shfl_xor(v, m, 64));
  return v;
}

// ---------- fused prep: mean | cvtx | cvtw | count ----------
__global__ __launch_bounds__(256) void k_prep(const float* __restrict__ ea,
                                              const float* __restrict__ x,
                                              const float* __restrict__ W1l,
                                              const float* __restrict__ W1r,
                                              const int* __restrict__ ei,
                                              float* __restrict__ meanacc,
                                              unsigned short* __restrict__ xb,
                                              unsigned short* __restrict__ Bfrag,
                                              int* __restrict__ deg){
  int b = blockIdx.x;
  if (b < NB_MEAN){
    // ---- edge_attr column sums ----
    float s0 = 0.f, s1 = 0.f, s2 = 0.f;
    for (int i = b * 256 + threadIdx.x; i < N_EDGESC; i += NB_MEAN * 256){
      s0 += ea[i*3+0]; s1 += ea[i*3+1]; s2 += ea[i*3+2];
    }
    s0 = wave_sum(s0); s1 = wave_sum(s1); s2 = wave_sum(s2);
    __shared__ float red[3][4];
    int lane = threadIdx.x & 63, w = threadIdx.x >> 6;
    if (lane == 0){ red[0][w] = s0; red[1][w] = s1; red[2][w] = s2; }
    __syncthreads();
    if (threadIdx.x == 0){
      float t0 = 0.f, t1 = 0.f, t2 = 0.f;
      for (int i = 0; i < 4; i++){ t0 += red[0][i]; t1 += red[1][i]; t2 += red[2][i]; }
      atomicAdd(&meanacc[0], t0); atomicAdd(&meanacc[1], t1); atomicAdd(&meanacc[2], t2);
    }
    return;
  }
  b -= NB_MEAN;
  if (b < NB_CVTX){
    // ---- x fp32 -> bf16 bits, zero pad rows ----
    size_t tid = (size_t)b * 256 + threadIdx.x;
    size_t base = tid * 4;
    const size_t NELEM = (size_t)N_NODESC * IN_DIMC;
    ushortx4 o;
    if (base + 3 < NELEM){
      float4 v = *(const float4*)(x + base);
      o[0] = (unsigned short)(__float_as_uint(v.x) >> 16);
      o[1] = (unsigned short)(__float_as_uint(v.y) >> 16);
      o[2] = (unsigned short)(__float_as_uint(v.z) >> 16);
      o[3] = (unsigned short)(__float_as_uint(v.w) >> 16);
    } else {
      #pragma unroll
      for (int f = 0; f < 4; f++){
        size_t i = base + f;
        float v = (i < NELEM) ? x[i] : 0.f;
        o[f] = (unsigned short)(__float_as_uint(v) >> 16);
      }
    }
    *(ushortx4*)(xb + base) = o;
    return;
  }
  b -= NB_CVTX;
  if (b < NB_CVTW){
    // ---- W1l/W1r -> MFMA B-frag layout: [mat][kblk][n][j] ----
    int idx = b * 256 + threadIdx.x;
    int mat = idx >> 15;
    int r   = idx & 32767;
    int k   = r >> 8, n = r & 255;
    float v = mat ? W1r[r] : W1l[r];
    int pos = (mat << 15) + (((k >> 3) << 8) + n) * 8 + (k & 7);
    Bfrag[pos] = (unsigned short)(__float_as_uint(v) >> 16);
    return;
  }
  b -= NB_CVTW;
  {
    // ---- degree count ----
    int e = b * 256 + threadIdx.x;
    if (e >= E_TOTC) return;
    int dst = (e < N_EDGESC) ? ei[N_EDGESC + e] : (e - N_EDGESC);
    atomicAdd(&deg[dst], 1);
  }
}

// ---------- single-block scan ----------
__global__ __launch_bounds__(1024) void k_scan(const int* __restrict__ deg,
                                               int* __restrict__ offsets,
                                               int* __restrict__ cursor){
  const int n = N_NODESC;
  const int T = 1024;
  const int CH = (n + T - 1) / T;
  int t = threadIdx.x;
  int beg = t * CH, end = min(beg + CH, n);
  int s = 0;
  for (int i = beg; i < end; i++) s += deg[i];
  __shared__ int sums[1024];
  sums[t] = s;
  __syncthreads();
  for (int off = 1; off < T; off <<= 1){
    int v = (t >= off) ? sums[t - off] : 0;
    __syncthreads();
    sums[t] += v;
    __syncthreads();
  }
  int run = sums[t] - s;
  for (int i = beg; i < end; i++){
    offsets[i] = run; cursor[i] = run; run += deg[i];
  }
  if (t == T - 1) offsets[n] = sums[T - 1];
}

// ---------- scatter: CSR perm + packed edge scalars (e0,e1,e2,ef2) ----------
__global__ __launch_bounds__(256) void k_scatter(const int* __restrict__ ei,
                                                 const float* __restrict__ ea,
                                                 const float* __restrict__ meanacc,
                                                 const float* __restrict__ W2e,
                                                 int* __restrict__ cursor,
                                                 int* __restrict__ srcp,
                                                 float4* __restrict__ epack){
  int e = blockIdx.x * blockDim.x + threadIdx.x;
  if (e >= E_TOTC) return;
  int src, dst; float e0, e1, e2;
  if (e < N_EDGESC){
    src = ei[e]; dst = ei[N_EDGESC + e];
    e0 = ea[e*3+0]; e1 = ea[e*3+1]; e2 = ea[e*3+2];
  } else {
    src = dst = e - N_EDGESC;
    const float inv = 1.0f / (float)N_EDGESC;
    e0 = meanacc[0]*inv; e1 = meanacc[1]*inv; e2 = meanacc[2]*inv;
  }
  int pos = atomicAdd(&cursor[dst], 1);
  srcp[pos] = src;
  float4 p; p.x = e0; p.y = e1; p.z = e2;
  p.w = e0*W2e[0] + e1*W2e[1] + e2*W2e[2];
  epack[pos] = p;
}

// ---------- MFMA dual GEMM: xl = x@W1l, xr = x@W1r (bf16 out) ----------
__global__ __launch_bounds__(256) void k_gemm_mfma(const unsigned short* __restrict__ xb,
                                                   const unsigned short* __restrict__ Bfrag,
                                                   unsigned short* __restrict__ xl,
                                                   unsigned short* __restrict__ xr){
  const int mat = blockIdx.y;
  const int r0  = blockIdx.x * 32;
  const int w = threadIdx.x >> 6, lane = threadIdx.x & 63;
  const int quad = lane >> 4, l16 = lane & 15;
  const unsigned short* Bm = Bfrag + ((size_t)mat << 15);
  unsigned short* C = mat ? xr : xl;

  short8 afr[2][4];
  #pragma unroll
  for (int ms = 0; ms < 2; ms++)
    #pragma unroll
    for (int ks = 0; ks < 4; ks++){
      const unsigned short* p = xb + (size_t)(r0 + ms*16 + l16) * IN_DIMC + ks*32 + quad*8;
      afr[ms][ks] = *reinterpret_cast<const short8*>(p);
    }
  const int n0 = w * 64;
  floatx4 acc[2][4];
  #pragma unroll
  for (int ms = 0; ms < 2; ms++)
    #pragma unroll
    for (int ns = 0; ns < 4; ns++){
      floatx4 z = {0.f, 0.f, 0.f, 0.f};
      acc[ms][ns] = z;
    }
  #pragma unroll
  for (int ks = 0; ks < 4; ks++){
    #pragma unroll
    for (int ns = 0; ns < 4; ns++){
      int n = n0 + ns*16 + l16;
      int kblk = ks*4 + quad;
      short8 bfr = *reinterpret_cast<const short8*>(Bm + ((size_t)kblk*256 + n)*8);
      acc[0][ns] = __builtin_amdgcn_mfma_f32_16x16x32_bf16(afr[0][ks], bfr, acc[0][ns], 0, 0, 0);
      acc[1][ns] = __builtin_amdgcn_mfma_f32_16x16x32_bf16(afr[1][ks], bfr, acc[1][ns], 0, 0, 0);
    }
  }
  #pragma unroll
  for (int ms = 0; ms < 2; ms++)
    #pragma unroll
    for (int ns = 0; ns < 4; ns++){
      int col = n0 + ns*16 + l16;
      #pragma unroll
      for (int rg = 0; rg < 4; rg++){
        int row = r0 + ms*16 + quad*4 + rg;
        C[(size_t)row * FDIM + col] = (unsigned short)(__float_as_uint(acc[ms][ns][rg]) >> 16);
      }
    }
}

// ---------- layer-1 FUSED, chunked two-phase, register constants ----------
__global__ __launch_bounds__(256) void k_attn1(const int* __restrict__ offsets,
                                               const int* __restrict__ srcp,
                                               const float4* __restrict__ epack,
                                               const unsigned short* __restrict__ xl,
                                               const unsigned short* __restrict__ xr,
                                               const float* __restrict__ W1e,
                                               const float* __restrict__ att1,
                                               const float* __restrict__ b1,
                                               const float* __restrict__ W2l,
                                               const float* __restrict__ W2r,
                                               float* __restrict__ sl,
                                               float* __restrict__ sr){
  const int n = blockIdx.x;
  const int t = threadIdx.x, lane = t & 63, w = t >> 6;
  const int f0 = lane * 4;
  // register-resident per-lane feature constants (phase A)
  float we0[4], we1[4], we2[4], av[4], xrv[4];
  #pragma unroll
  for (int f = 0; f < 4; f++){
    we0[f] = W1e[f0 + f];
    we1[f] = W1e[FDIM + f0 + f];
    we2[f] = W1e[2*FDIM + f0 + f];
    av[f]  = att1[f0 + f];
    xrv[f] = bits2f(xr[(size_t)n * FDIM + f0 + f]);
  }
  __shared__ unsigned short xls[CHUNK][FDIM];
  __shared__ float lgs[HEADSC][CHUNK];
  __shared__ float als[HEADSC][CHUNK];
  const int beg = offsets[n], end = offsets[n + 1];
  float m = -1e30f, den = 0.f, acc = 0.f;
  for (int c0 = beg; c0 < end; c0 += CHUNK){
    int cnt = min(CHUNK, end - c0);
    // ---- phase A: wave w owns edges i = w, w+4, ... ----
    for (int i = w; i < cnt; i += 4){
      int j = c0 + i;
      int src = srcp[j];
      float4 ep = epack[j];
      ushortx4 raw = *(const ushortx4*)(xl + (size_t)src * FDIM + f0);
      float pp = 0.f;
      #pragma unroll
      for (int f = 0; f < 4; f++){
        float v = bits2f(raw[f]) + xrv[f];
        v = fmaf(ep.x, we0[f], v);
        v = fmaf(ep.y, we1[f], v);
        v = fmaf(ep.z, we2[f], v);
        v = fmaxf(v, NEG_SLOPE * v);      // leaky relu (slope<1)
        pp = fmaf(v, av[f], pp);
      }
      pp += __shfl_xor(pp, 1, 64);
      pp += __shfl_xor(pp, 2, 64);
      pp += __shfl_xor(pp, 4, 64);
      pp += __shfl_xor(pp, 8, 64);
      if ((lane & 15) == 0) lgs[lane >> 4][i] = pp;
      *(ushortx4*)&xls[i][f0] = raw;
    }
    __syncthreads();
    // ---- phase B: online softmax update for head w ----
    float cm = -1e30f;
    for (int i = 0; i < cnt; i++) cm = fmaxf(cm, lgs[w][i]);
    float mn = fmaxf(m, cm);
    float corr = __expf(m - mn);
    float alv = (lane < cnt) ? __expf(lgs[w][lane] - mn) : 0.f;
    if (lane < CHUNK) als[w][lane] = alv;      // wave-internal share
    den = den * corr + wave_sum(alv);
    acc *= corr;
    for (int i = 0; i < cnt; i++)
      acc = fmaf(als[w][i], bits2f(xls[i][t]), acc);
    m = mn;
    __syncthreads();
  }
  float h = acc / den + b1[t];
  h = (h > 0.f) ? h : (__expf(h) - 1.f);   // ELU
  float a = wave_sum(h * W2l[t]);
  float bb = wave_sum(h * W2r[t]);
  __shared__ float sred[2][4];
  if (lane == 0){ sred[0][w] = a; sred[1][w] = bb; }
  __syncthreads();
  if (t == 0){
    sl[n] = sred[0][0] + sred[0][1] + sred[0][2] + sred[0][3];
    sr[n] = sred[1][0] + sred[1][1] + sred[1][2] + sred[1][3];
  }
}

// ---------- layer-2 FUSED: edge logits + online softmax -> scores (+global max) ----------
// grid is exactly N_NODESC/4 blocks: every wave has a valid node.
__global__ __launch_bounds__(256) void k_attn2(const int* __restrict__ offsets,
                                               const int* __restrict__ srcp,
                                               const float4* __restrict__ epack,
                                               const float* __restrict__ att2,
                                               const float* __restrict__ b2p,
                                               const float* __restrict__ sl,
                                               const float* __restrict__ sr,
                                               float* __restrict__ scores,
                                               float* __restrict__ out,
                                               unsigned* __restrict__ redmax);

__device__ __forceinline__ unsigned fkey(float f){
  unsigned u = __float_as_uint(f);
  return u ^ ((u >> 31) ? 0xFFFFFFFFu : 0x80000000u);
}
__device__ __forceinline__ float funkey(unsigned k){
  unsigned u = (k >> 31) ? (k ^ 0x80000000u) : ~k;
  return __uint_as_float(u);
}

__global__ __launch_bounds__(256) void k_attn2(const int* __restrict__ offsets,
                                               const int* __restrict__ srcp,
                                               const float4* __restrict__ epack,
                                               const float* __restrict__ att2,
                                               const float* __restrict__ b2p,
                                               const float* __restrict__ sl,
                                               const float* __restrict__ sr,
                                               float* __restrict__ scores,
                                               float* __restrict__ out,
                                               unsigned* __restrict__ redmax){
  int t = threadIdx.x, lane = t & 63, w = t >> 6;
  int n = blockIdx.x * 4 + w;
  const float attv = att2[0];
  const float srn = sr[n];
  int beg = offsets[n], end = offsets[n + 1];
  float m = -1e30f, den = 0.f, num = 0.f;
  for (int j = beg + lane; j < end; j += 64){
    float slv = sl[srcp[j]];
    float v = slv + srn + epack[j].w;
    v = fmaxf(v, NEG_SLOPE * v);
    float lg = v * attv;
    float mn = fmaxf(m, lg);
    float corr = __expf(m - mn);
    float pe   = __expf(lg - mn);
    den = den * corr + pe;
    num = num * corr + pe * slv;
    m = mn;
  }
  float mg = wave_max(m);
  float scale = __expf(m - mg);
  float deng = wave_sum(den * scale);
  float numg = wave_sum(num * scale);
  float s = numg / deng + b2p[0];
  __shared__ float smx[4];
  if (lane == 0){
    scores[n] = s;
    out[N_NODESC + n] = s;
    smx[w] = s;
  }
  __syncthreads();
  if (t == 0){
    float m4 = fmaxf(fmaxf(smx[0], smx[1]), fmaxf(smx[2], smx[3]));
    atomicMax(redmax, fkey(m4));
  }
}

__global__ __launch_bounds__(256) void k_smax_sum(const float* __restrict__ scores,
                                                  const unsigned* __restrict__ redmax,
                                                  float* __restrict__ redsum){
  float mx = funkey(*redmax);
  float s = 0.f;
  for (int i = blockIdx.x * blockDim.x + threadIdx.x; i < N_NODESC;
       i += gridDim.x * blockDim.x)
    s += __expf(scores[i] - mx);
  s = wave_sum(s);
  __shared__ float ws_[4];
  int lane = threadIdx.x & 63, w = threadIdx.x >> 6;
  if (lane == 0) ws_[w] = s;
  __syncthreads();
  if (threadIdx.x == 0){
    float t = 0.f;
    for (int i = 0; i < 4; i++) t += ws_[i];
    atomicAdd(redsum, t);
  }
}

__global__ __launch_bounds__(256) void k_smax_write(const float* __restrict__ scores,
                                                    const unsigned* __restrict__ redmax,
                                                    const float* __restrict__ redsum,
                                                    float* __restrict__ out){
  int i = blockIdx.x * blockDim.x + threadIdx.x;
  if (i >= N_NODESC) return;
  float mx = funkey(*redmax);
  float inv = 1.0f / (*redsum);
  out[i] = __expf(scores[i] - mx) * inv;
}

extern "C" void kernel_launch(void* const* d_in, const int* in_sizes, int n_in,
                              void* d_out, int out_size, void* d_ws, size_t ws_size,
                              hipStream_t stream) {
  const float* x    = (const float*)d_in[0];
  const float* ea   = (const float*)d_in[1];
  const float* W1l  = (const float*)d_in[2];
  const float* W1r  = (const float*)d_in[3];
  const float* W1e  = (const float*)d_in[4];
  const float* att1 = (const float*)d_in[5];
  const float* b1   = (const float*)d_in[6];
  const float* W2l  = (const float*)d_in[7];
  const float* W2r  = (const float*)d_in[8];
  const float* W2e  = (const float*)d_in[9];
  const float* att2 = (const float*)d_in[10];
  const float* b2   = (const float*)d_in[11];
  const int*   ei   = (const int*)d_in[12];
  float* out = (float*)d_out;

  char* w = (char*)d_ws;
  size_t off = 0;
  auto alloc = [&](size_t bytes) -> char* {
    char* p = w + off;
    off = (off + bytes + 255) & ~(size_t)255;
    return p;
  };
  // ---- zero zone (memset every call) ----
  float*    meanacc = (float*)alloc(16);
  unsigned* redmax  = (unsigned*)alloc(8);
  float*    redsum  = (float*)((char*)redmax + 4);
  int*      deg     = (int*)alloc((size_t)N_NODESC * 4);
  size_t zero_bytes = off;
  // ---- rest ----
  int*    offsets = (int*)alloc((size_t)(N_NODESC + 1) * 4);
  int*    cursor  = (int*)alloc((size_t)N_NODESC * 4);
  int*    srcp    = (int*)alloc((size_t)E_TOTC * 4);
  float4* epack   = (float4*)alloc((size_t)E_TOTC * 16);
  float*  sl      = (float*)alloc((size_t)N_NODESC * 4);
  float*  sr      = (float*)alloc((size_t)N_NODESC * 4);
  float*  scores  = (float*)alloc((size_t)N_NODESC * 4);
  unsigned short* xb    = (unsigned short*)alloc((size_t)MPAD * IN_DIMC * 2);
  unsigned short* Bfrag = (unsigned short*)alloc((size_t)2 * 128 * 256 * 2);
  unsigned short* xl    = (unsigned short*)alloc((size_t)MPAD * FDIM * 2);
  unsigned short* xr    = (unsigned short*)alloc((size_t)MPAD * FDIM * 2);
  (void)ws_size; (void)in_sizes; (void)n_in; (void)out_size;

  hipMemsetAsync(d_ws, 0, zero_bytes, stream);

  k_prep <<<NB_MEAN + NB_CVTX + NB_CVTW + NB_COUNT, 256, 0, stream>>>(
      ea, x, W1l, W1r, ei, meanacc, xb, Bfrag, deg);
  k_scan <<<1, 1024, 0, stream>>>(deg, offsets, cursor);
  k_scatter<<<(E_TOTC + 255) / 256, 256, 0, stream>>>(ei, ea, meanacc, W2e,
                                                      cursor, srcp, epack);
  {
    dim3 g(MPAD / 32, 2);
    k_gemm_mfma<<<g, 256, 0, stream>>>(xb, Bfrag, xl, xr);
  }
  k_attn1 <<<N_NODESC, 256, 0, stream>>>(offsets, srcp, epack, xl, xr,
                                         W1e, att1, b1, W2l, W2r, sl, sr);
  k_attn2 <<<N_NODESC / 4, 256, 0, stream>>>(offsets, srcp, epack, att2, b2,
                                             sl, sr, scores, out, redmax);
  k_smax_sum <<<256, 256, 0, stream>>>(scores, redmax, redsum);
  k_smax_write<<<(N_NODESC + 255) / 256, 256, 0, stream>>>(scores, redmax, redsum, out);
}

// Round 6
// 660.278 us; speedup vs baseline: 1.0531x; 1.0531x over previous
//
#include <hip/hip_runtime.h>
#include <hip/hip_bf16.h>

typedef __hip_bfloat16 bf16;
typedef __attribute__((ext_vector_type(8))) short short8;
typedef __attribute__((ext_vector_type(4))) float floatx4;
typedef __attribute__((ext_vector_type(4))) unsigned short ushortx4;

#define N_NODESC 50000
#define MPAD     50016     // padded to 32-row tiles
#define N_EDGESC 800000
#define E_TOTC   850000    // + self loops
#define IN_DIMC  128
#define FDIM     256       // HEADS*HID
#define HEADSC   4
#define HIDC     64
#define NEG_SLOPE 0.2f
#define CHUNK    32

__device__ __forceinline__ float bits2f(unsigned short b){
  return __uint_as_float(((unsigned)b) << 16);
}

__device__ __forceinline__ float wave_sum(float v){
  #pragma unroll
  for (int m = 32; m > 0; m >>= 1) v += __shfl_xor(v, m, 64);
  return v;
}
__device__ __forceinline__ float wave_max(float v){
  #pragma unroll
  for (int m = 32; m > 0; m >>= 1) v = fmaxf(v, __shfl_xor(v, m, 64));
  return v;
}

// ---------- edge_attr column means (for self-loop fill) ----------
__global__ __launch_bounds__(256) void k_mean(const float* __restrict__ ea,
                                              float* __restrict__ meanacc){
  float s0 = 0.f, s1 = 0.f, s2 = 0.f;
  for (int i = blockIdx.x * blockDim.x + threadIdx.x; i < N_EDGESC;
       i += gridDim.x * blockDim.x){
    s0 += ea[i*3+0]; s1 += ea[i*3+1]; s2 += ea[i*3+2];
  }
  s0 = wave_sum(s0); s1 = wave_sum(s1); s2 = wave_sum(s2);
  __shared__ float red[3][4];
  int lane = threadIdx.x & 63, w = threadIdx.x >> 6;
  if (lane == 0){ red[0][w] = s0; red[1][w] = s1; red[2][w] = s2; }
  __syncthreads();
  if (threadIdx.x == 0){
    float t0 = 0.f, t1 = 0.f, t2 = 0.f;
    for (int i = 0; i < 4; i++){ t0 += red[0][i]; t1 += red[1][i]; t2 += red[2][i]; }
    atomicAdd(&meanacc[0], t0); atomicAdd(&meanacc[1], t1); atomicAdd(&meanacc[2], t2);
  }
}

// ---------- convert x (fp32) -> xb (bf16 bits), zero pad rows ----------
__global__ __launch_bounds__(256) void k_cvtx(const float* __restrict__ x,
                                              unsigned short* __restrict__ xb){
  size_t tid = (size_t)blockIdx.x * 256 + threadIdx.x;
  size_t base = tid * 4;
  const size_t NELEM = (size_t)N_NODESC * IN_DIMC;
  ushortx4 o;
  if (base + 3 < NELEM){
    float4 v = *(const float4*)(x + base);
    o[0] = (unsigned short)(__float_as_uint(v.x) >> 16);
    o[1] = (unsigned short)(__float_as_uint(v.y) >> 16);
    o[2] = (unsigned short)(__float_as_uint(v.z) >> 16);
    o[3] = (unsigned short)(__float_as_uint(v.w) >> 16);
  } else {
    #pragma unroll
    for (int f = 0; f < 4; f++){
      size_t i = base + f;
      float v = (i < NELEM) ? x[i] : 0.f;
      o[f] = (unsigned short)(__float_as_uint(v) >> 16);
    }
  }
  *(ushortx4*)(xb + base) = o;
}

// ---------- convert W1l,W1r -> MFMA-frag-contiguous bf16 layout ----------
__global__ __launch_bounds__(256) void k_cvtw(const float* __restrict__ W1l,
                                              const float* __restrict__ W1r,
                                              unsigned short* __restrict__ Bfrag){
  int idx = blockIdx.x * 256 + threadIdx.x;   // < 65536
  int mat = idx >> 15;
  int r   = idx & 32767;       // k*256+n
  int k   = r >> 8, n = r & 255;
  float v = mat ? W1r[r] : W1l[r];
  int pos = (mat << 15) + (((k >> 3) << 8) + n) * 8 + (k & 7);
  Bfrag[pos] = (unsigned short)(__float_as_uint(v) >> 16);
}

// ---------- CSR build: count (+rank), scan, scatter (atomic-free) ----------
__global__ __launch_bounds__(256) void k_count(const int* __restrict__ ei,
                                               int* __restrict__ deg,
                                               int* __restrict__ rank){
  int e = blockIdx.x * blockDim.x + threadIdx.x;
  if (e >= E_TOTC) return;
  int dst = (e < N_EDGESC) ? ei[N_EDGESC + e] : (e - N_EDGESC);
  rank[e] = atomicAdd(&deg[dst], 1);
}

__global__ __launch_bounds__(1024) void k_scan(const int* __restrict__ deg,
                                               int* __restrict__ offsets){
  const int n = N_NODESC;
  const int T = 1024;
  const int CH = (n + T - 1) / T;
  int t = threadIdx.x;
  int beg = t * CH, end = min(beg + CH, n);
  int s = 0;
  for (int i = beg; i < end; i++) s += deg[i];
  __shared__ int sums[1024];
  sums[t] = s;
  __syncthreads();
  for (int off = 1; off < T; off <<= 1){
    int v = (t >= off) ? sums[t - off] : 0;
    __syncthreads();
    sums[t] += v;
    __syncthreads();
  }
  int run = sums[t] - s;
  for (int i = beg; i < end; i++){
    offsets[i] = run; run += deg[i];
  }
  if (t == T - 1) offsets[n] = sums[T - 1];
}

__global__ __launch_bounds__(256) void k_scatter(const int* __restrict__ ei,
                                                 const float* __restrict__ ea,
                                                 const float* __restrict__ meanacc,
                                                 const float* __restrict__ W2e,
                                                 const int* __restrict__ offsets,
                                                 const int* __restrict__ rank,
                                                 int* __restrict__ srcp,
                                                 float4* __restrict__ epack,
                                                 float* __restrict__ ef2){
  int e = blockIdx.x * blockDim.x + threadIdx.x;
  if (e >= E_TOTC) return;
  int src, dst; float e0, e1, e2;
  if (e < N_EDGESC){
    src = ei[e]; dst = ei[N_EDGESC + e];
    e0 = ea[e*3+0]; e1 = ea[e*3+1]; e2 = ea[e*3+2];
  } else {
    src = dst = e - N_EDGESC;
    const float inv = 1.0f / (float)N_EDGESC;
    e0 = meanacc[0]*inv; e1 = meanacc[1]*inv; e2 = meanacc[2]*inv;
  }
  int pos = offsets[dst] + rank[e];
  srcp[pos] = src;
  float f2 = e0*W2e[0] + e1*W2e[1] + e2*W2e[2];
  float4 p; p.x = e0; p.y = e1; p.z = e2; p.w = f2;
  epack[pos] = p;
  ef2[pos] = f2;
}

// ---------- MFMA dual GEMM: xl = x@W1l, xr = x@W1r (bf16 out) ----------
__global__ __launch_bounds__(256) void k_gemm_mfma(const unsigned short* __restrict__ xb,
                                                   const unsigned short* __restrict__ Bfrag,
                                                   unsigned short* __restrict__ xl,
                                                   unsigned short* __restrict__ xr){
  const int mat = blockIdx.y;
  const int r0  = blockIdx.x * 32;
  const int w = threadIdx.x >> 6, lane = threadIdx.x & 63;
  const int quad = lane >> 4, l16 = lane & 15;
  const unsigned short* Bm = Bfrag + ((size_t)mat << 15);
  unsigned short* C = mat ? xr : xl;

  short8 afr[2][4];
  #pragma unroll
  for (int ms = 0; ms < 2; ms++)
    #pragma unroll
    for (int ks = 0; ks < 4; ks++){
      const unsigned short* p = xb + (size_t)(r0 + ms*16 + l16) * IN_DIMC + ks*32 + quad*8;
      afr[ms][ks] = *reinterpret_cast<const short8*>(p);
    }
  const int n0 = w * 64;
  floatx4 acc[2][4];
  #pragma unroll
  for (int ms = 0; ms < 2; ms++)
    #pragma unroll
    for (int ns = 0; ns < 4; ns++){
      floatx4 z = {0.f, 0.f, 0.f, 0.f};
      acc[ms][ns] = z;
    }
  #pragma unroll
  for (int ks = 0; ks < 4; ks++){
    #pragma unroll
    for (int ns = 0; ns < 4; ns++){
      int n = n0 + ns*16 + l16;
      int kblk = ks*4 + quad;
      short8 bfr = *reinterpret_cast<const short8*>(Bm + ((size_t)kblk*256 + n)*8);
      acc[0][ns] = __builtin_amdgcn_mfma_f32_16x16x32_bf16(afr[0][ks], bfr, acc[0][ns], 0, 0, 0);
      acc[1][ns] = __builtin_amdgcn_mfma_f32_16x16x32_bf16(afr[1][ks], bfr, acc[1][ns], 0, 0, 0);
    }
  }
  #pragma unroll
  for (int ms = 0; ms < 2; ms++)
    #pragma unroll
    for (int ns = 0; ns < 4; ns++){
      int col = n0 + ns*16 + l16;
      #pragma unroll
      for (int rg = 0; rg < 4; rg++){
        int row = r0 + ms*16 + quad*4 + rg;
        C[(size_t)row * FDIM + col] = (unsigned short)(__float_as_uint(acc[ms][ns][rg]) >> 16);
      }
    }
}

// ---------- layer-1 FUSED, chunked two-phase, register constants ----------
__global__ __launch_bounds__(256) void k_attn1(const int* __restrict__ offsets,
                                               const int* __restrict__ srcp,
                                               const float4* __restrict__ epack,
                                               const unsigned short* __restrict__ xl,
                                               const unsigned short* __restrict__ xr,
                                               const float* __restrict__ W1e,
                                               const float* __restrict__ att1,
                                               const float* __restrict__ b1,
                                               const float* __restrict__ W2l,
                                               const float* __restrict__ W2r,
                                               float* __restrict__ sl,
                                               float* __restrict__ sr){
  const int n = blockIdx.x;
  const int t = threadIdx.x, lane = t & 63, w = t >> 6;
  const int f0 = lane * 4;
  float we0[4], we1[4], we2[4], av[4], xrv[4];
  #pragma unroll
  for (int f = 0; f < 4; f++){
    we0[f] = W1e[f0 + f];
    we1[f] = W1e[FDIM + f0 + f];
    we2[f] = W1e[2*FDIM + f0 + f];
    av[f]  = att1[f0 + f];
    xrv[f] = bits2f(xr[(size_t)n * FDIM + f0 + f]);
  }
  __shared__ unsigned short xls[CHUNK][FDIM];
  __shared__ float lgs[HEADSC][CHUNK];
  __shared__ float als[HEADSC][CHUNK];
  const int beg = offsets[n], end = offsets[n + 1];
  float m = -1e30f, den = 0.f, acc = 0.f;
  for (int c0 = beg; c0 < end; c0 += CHUNK){
    int cnt = min(CHUNK, end - c0);
    // ---- phase A: wave w owns edges i = w, w+4, ... ----
    for (int i = w; i < cnt; i += 4){
      int j = c0 + i;
      int src = srcp[j];
      float4 ep = epack[j];
      ushortx4 raw = *(const ushortx4*)(xl + (size_t)src * FDIM + f0);
      float pp = 0.f;
      #pragma unroll
      for (int f = 0; f < 4; f++){
        float v = bits2f(raw[f]) + xrv[f];
        v = fmaf(ep.x, we0[f], v);
        v = fmaf(ep.y, we1[f], v);
        v = fmaf(ep.z, we2[f], v);
        v = fmaxf(v, NEG_SLOPE * v);      // leaky relu (slope<1)
        pp = fmaf(v, av[f], pp);
      }
      pp += __shfl_xor(pp, 1, 64);
      pp += __shfl_xor(pp, 2, 64);
      pp += __shfl_xor(pp, 4, 64);
      pp += __shfl_xor(pp, 8, 64);
      if ((lane & 15) == 0) lgs[lane >> 4][i] = pp;
      *(ushortx4*)&xls[i][f0] = raw;
    }
    __syncthreads();
    // ---- phase B: online softmax update for head w ----
    float cm = -1e30f;
    for (int i = 0; i < cnt; i++) cm = fmaxf(cm, lgs[w][i]);
    float mn = fmaxf(m, cm);
    float corr = __expf(m - mn);
    float alv = (lane < cnt) ? __expf(lgs[w][lane] - mn) : 0.f;
    if (lane < CHUNK) als[w][lane] = alv;
    den = den * corr + wave_sum(alv);
    acc *= corr;
    for (int i = 0; i < cnt; i++)
      acc = fmaf(als[w][i], bits2f(xls[i][t]), acc);
    m = mn;
    __syncthreads();
  }
  float h = acc / den + b1[t];
  h = (h > 0.f) ? h : (__expf(h) - 1.f);   // ELU
  float a = wave_sum(h * W2l[t]);
  float bb = wave_sum(h * W2r[t]);
  __shared__ float sred[2][4];
  if (lane == 0){ sred[0][w] = a; sred[1][w] = bb; }
  __syncthreads();
  if (t == 0){
    sl[n] = sred[0][0] + sred[0][1] + sred[0][2] + sred[0][3];
    sr[n] = sred[1][0] + sred[1][1] + sred[1][2] + sred[1][3];
  }
}

// ---------- layer-2 FUSED: edge logits + online softmax -> scores (+global max) ----------
__device__ __forceinline__ unsigned fkey(float f){
  unsigned u = __float_as_uint(f);
  return u ^ ((u >> 31) ? 0xFFFFFFFFu : 0x80000000u);
}
__device__ __forceinline__ float funkey(unsigned k){
  unsigned u = (k >> 31) ? (k ^ 0x80000000u) : ~k;
  return __uint_as_float(u);
}

__global__ __launch_bounds__(256) void k_attn2(const int* __restrict__ offsets,
                                               const int* __restrict__ srcp,
                                               const float* __restrict__ ef2,
                                               const float* __restrict__ att2,
                                               const float* __restrict__ b2p,
                                               const float* __restrict__ sl,
                                               const float* __restrict__ sr,
                                               float* __restrict__ scores,
                                               float* __restrict__ out,
                                               unsigned* __restrict__ redmax){
  int t = threadIdx.x, lane = t & 63, w = t >> 6;
  int n = blockIdx.x * 4 + w;
  const float attv = att2[0];
  const float srn = sr[n];
  int beg = offsets[n], end = offsets[n + 1];
  float m = -1e30f, den = 0.f, num = 0.f;
  for (int j = beg + lane; j < end; j += 64){
    float slv = sl[srcp[j]];
    float v = slv + srn + ef2[j];
    v = fmaxf(v, NEG_SLOPE * v);
    float lg = v * attv;
    float mn = fmaxf(m, lg);
    float corr = __expf(m - mn);
    float pe   = __expf(lg - mn);
    den = den * corr + pe;
    num = num * corr + pe * slv;
    m = mn;
  }
  float mg = wave_max(m);
  float scale = __expf(m - mg);
  float deng = wave_sum(den * scale);
  float numg = wave_sum(num * scale);
  float s = numg / deng + b2p[0];
  __shared__ float smx[4];
  if (lane == 0){
    scores[n] = s;
    out[N_NODESC + n] = s;
    smx[w] = s;
  }
  __syncthreads();
  if (t == 0){
    float m4 = fmaxf(fmaxf(smx[0], smx[1]), fmaxf(smx[2], smx[3]));
    atomicMax(redmax, fkey(m4));
  }
}

__global__ __launch_bounds__(256) void k_smax_sum(const float* __restrict__ scores,
                                                  const unsigned* __restrict__ redmax,
                                                  float* __restrict__ redsum){
  float mx = funkey(*redmax);
  float s = 0.f;
  for (int i = blockIdx.x * blockDim.x + threadIdx.x; i < N_NODESC;
       i += gridDim.x * blockDim.x)
    s += __expf(scores[i] - mx);
  s = wave_sum(s);
  __shared__ float ws_[4];
  int lane = threadIdx.x & 63, w = threadIdx.x >> 6;
  if (lane == 0) ws_[w] = s;
  __syncthreads();
  if (threadIdx.x == 0){
    float t = 0.f;
    for (int i = 0; i < 4; i++) t += ws_[i];
    atomicAdd(redsum, t);
  }
}

__global__ __launch_bounds__(256) void k_smax_write(const float* __restrict__ scores,
                                                    const unsigned* __restrict__ redmax,
                                                    const float* __restrict__ redsum,
                                                    float* __restrict__ out){
  int i = blockIdx.x * blockDim.x + threadIdx.x;
  if (i >= N_NODESC) return;
  float mx = funkey(*redmax);
  float inv = 1.0f / (*redsum);
  out[i] = __expf(scores[i] - mx) * inv;
}

extern "C" void kernel_launch(void* const* d_in, const int* in_sizes, int n_in,
                              void* d_out, int out_size, void* d_ws, size_t ws_size,
                              hipStream_t stream) {
  const float* x    = (const float*)d_in[0];
  const float* ea   = (const float*)d_in[1];
  const float* W1l  = (const float*)d_in[2];
  const float* W1r  = (const float*)d_in[3];
  const float* W1e  = (const float*)d_in[4];
  const float* att1 = (const float*)d_in[5];
  const float* b1   = (const float*)d_in[6];
  const float* W2l  = (const float*)d_in[7];
  const float* W2r  = (const float*)d_in[8];
  const float* W2e  = (const float*)d_in[9];
  const float* att2 = (const float*)d_in[10];
  const float* b2   = (const float*)d_in[11];
  const int*   ei   = (const int*)d_in[12];
  float* out = (float*)d_out;

  char* w = (char*)d_ws;
  size_t off = 0;
  auto alloc = [&](size_t bytes) -> char* {
    char* p = w + off;
    off = (off + bytes + 255) & ~(size_t)255;
    return p;
  };
  // ---- zero zone (memset every call) ----
  float*    meanacc = (float*)alloc(16);
  unsigned* redmax  = (unsigned*)alloc(8);
  float*    redsum  = (float*)((char*)redmax + 4);
  int*      deg     = (int*)alloc((size_t)N_NODESC * 4);
  size_t zero_bytes = off;
  // ---- rest ----
  int*    offsets = (int*)alloc((size_t)(N_NODESC + 1) * 4);
  int*    rank    = (int*)alloc((size_t)E_TOTC * 4);
  int*    srcp    = (int*)alloc((size_t)E_TOTC * 4);
  float4* epack   = (float4*)alloc((size_t)E_TOTC * 16);
  float*  ef2     = (float*)alloc((size_t)E_TOTC * 4);
  float*  sl      = (float*)alloc((size_t)N_NODESC * 4);
  float*  sr      = (float*)alloc((size_t)N_NODESC * 4);
  float*  scores  = (float*)alloc((size_t)N_NODESC * 4);
  unsigned short* xb    = (unsigned short*)alloc((size_t)MPAD * IN_DIMC * 2);
  unsigned short* Bfrag = (unsigned short*)alloc((size_t)2 * 128 * 256 * 2);
  unsigned short* xl    = (unsigned short*)alloc((size_t)MPAD * FDIM * 2);
  unsigned short* xr    = (unsigned short*)alloc((size_t)MPAD * FDIM * 2);
  (void)ws_size; (void)in_sizes; (void)n_in; (void)out_size;

  hipMemsetAsync(d_ws, 0, zero_bytes, stream);

  k_mean  <<<400, 256, 0, stream>>>(ea, meanacc);
  k_cvtx  <<<(int)(((size_t)MPAD * IN_DIMC / 4 + 255) / 256), 256, 0, stream>>>(x, xb);
  k_cvtw  <<<256, 256, 0, stream>>>(W1l, W1r, Bfrag);
  k_count <<<(E_TOTC + 255) / 256, 256, 0, stream>>>(ei, deg, rank);
  k_scan  <<<1, 1024, 0, stream>>>(deg, offsets);
  k_scatter<<<(E_TOTC + 255) / 256, 256, 0, stream>>>(ei, ea, meanacc, W2e,
                                                      offsets, rank, srcp, epack, ef2);
  {
    dim3 g(MPAD / 32, 2);
    k_gemm_mfma<<<g, 256, 0, stream>>>(xb, Bfrag, xl, xr);
  }
  k_attn1 <<<N_NODESC, 256, 0, stream>>>(offsets, srcp, epack, xl, xr,
                                         W1e, att1, b1, W2l, W2r, sl, sr);
  k_attn2 <<<N_NODESC / 4, 256, 0, stream>>>(offsets, srcp, ef2, att2, b2,
                                             sl, sr, scores, out, redmax);
  k_smax_sum <<<256, 256, 0, stream>>>(scores, redmax, redsum);
  k_smax_write<<<(N_NODESC + 255) / 256, 256, 0, stream>>>(scores, redmax, redsum, out);
}